// Round 2
// baseline (786.101 us; speedup 1.0000x reference)
//
#include <hip/hip_runtime.h>

#define N_SEGMENTS 50000
#define N_ROWS     1600000
#define N_FEAT     64

// ---------- Phase A: histogram of segment ids (int atomics, L2-side) ----------
__global__ void hist_kernel(const int* __restrict__ idx, int* __restrict__ counts) {
    int i = blockIdx.x * 256 + threadIdx.x;
    if (i < N_ROWS) atomicAdd(&counts[idx[i]], 1);
}

// ---------- Phase B: exclusive scan of counts (one 1024-thread block) ----------
__device__ __forceinline__ int wave_incl_scan(int v) {
    int lane = threadIdx.x & 63;
#pragma unroll
    for (int d = 1; d < 64; d <<= 1) {
        int t = __shfl_up(v, d, 64);
        if (lane >= d) v += t;
    }
    return v;
}

__global__ void scan_kernel(const int* __restrict__ counts,
                            int* __restrict__ seg_start,
                            int* __restrict__ cursor) {
    __shared__ int wave_off[16];   // per-wave exclusive offsets within chunk
    __shared__ int s_carry;
    const int tid  = threadIdx.x;
    const int lane = tid & 63;
    const int wid  = tid >> 6;
    if (tid == 0) s_carry = 0;
    __syncthreads();

    for (int base = 0; base < N_SEGMENTS; base += 1024) {
        int i = base + tid;
        int v = (i < N_SEGMENTS) ? counts[i] : 0;
        int incl = wave_incl_scan(v);
        if (lane == 63) wave_off[wid] = incl;          // wave totals
        __syncthreads();
        if (wid == 0) {
            int ws    = (lane < 16) ? wave_off[lane] : 0;
            int wincl = wave_incl_scan(ws);
            if (lane < 16) wave_off[lane] = wincl - ws; // exclusive wave offset
        }
        __syncthreads();
        int excl = incl - v + wave_off[wid] + s_carry;  // global exclusive
        if (i < N_SEGMENTS) { seg_start[i] = excl; cursor[i] = excl; }
        __syncthreads();                                 // all reads of s_carry done
        if (tid == 1023) s_carry = excl + v;             // carry = inclusive of chunk end
        __syncthreads();
    }
    if (tid == 0) seg_start[N_SEGMENTS] = s_carry;       // == N_ROWS
}

// ---------- Phase C: scatter row ids into segment-sorted order ----------
__global__ void scatter_kernel(const int* __restrict__ idx,
                               int* __restrict__ cursor,
                               int* __restrict__ rowids) {
    int i = blockIdx.x * 256 + threadIdx.x;
    if (i < N_ROWS) {
        int s = idx[i];
        int p = atomicAdd(&cursor[s], 1);
        rowids[p] = i;
    }
}

// ---------- Phase D: one wave per segment, no atomics ----------
__global__ void __launch_bounds__(256)
reduce_kernel(const float* __restrict__ in,
              const int*   __restrict__ rowids,
              const int*   __restrict__ seg_start,
              float*       __restrict__ out) {
    const int wid  = threadIdx.x >> 6;
    const int lane = threadIdx.x & 63;
    const int seg  = blockIdx.x * 4 + wid;
    if (seg >= N_SEGMENTS) return;

    const int beg = seg_start[seg];
    const int end = seg_start[seg + 1];

    float acc = 0.f;
    int r = beg;
    for (; r + 4 <= end; r += 4) {
        // rowids[r..r+3] are wave-uniform reads (broadcast); row loads are
        // 64 lanes x 4B contiguous = one coalesced 256B transaction each.
        int r0 = rowids[r], r1 = rowids[r + 1], r2 = rowids[r + 2], r3 = rowids[r + 3];
        float v0 = in[(long long)r0 * N_FEAT + lane];
        float v1 = in[(long long)r1 * N_FEAT + lane];
        float v2 = in[(long long)r2 * N_FEAT + lane];
        float v3 = in[(long long)r3 * N_FEAT + lane];
        acc += v0; acc += v1; acc += v2; acc += v3;
    }
    for (; r < end; ++r)
        acc += in[(long long)rowids[r] * N_FEAT + lane];

    out[(long long)seg * N_FEAT + lane] = acc;   // every segment written -> no d_out memset needed
}

extern "C" void kernel_launch(void* const* d_in, const int* in_sizes, int n_in,
                              void* d_out, int out_size, void* d_ws, size_t ws_size,
                              hipStream_t stream) {
    const float* in  = (const float*)d_in[0];
    const int*   idx = (const int*)d_in[1];
    float*       out = (float*)d_out;

    // Workspace layout (ints), 64-element aligned blocks:
    int* counts    = (int*)d_ws;             // 50000
    int* seg_start = counts + 50048;         // 50001
    int* cursor    = seg_start + 50048;      // 50000
    int* rowids    = cursor + 50048;         // 1600000
    // total ~7.0 MB

    // d_ws is poisoned 0xAA before every call -> zero the histogram.
    hipMemsetAsync(counts, 0, N_SEGMENTS * sizeof(int), stream);

    const int ROW_BLOCKS = (N_ROWS + 255) / 256;           // 6250
    hist_kernel   <<<ROW_BLOCKS, 256, 0, stream>>>(idx, counts);
    scan_kernel   <<<1, 1024, 0, stream>>>(counts, seg_start, cursor);
    scatter_kernel<<<ROW_BLOCKS, 256, 0, stream>>>(idx, cursor, rowids);

    const int SEG_BLOCKS = (N_SEGMENTS + 3) / 4;           // 12500 (4 waves/block)
    reduce_kernel <<<SEG_BLOCKS, 256, 0, stream>>>(in, rowids, seg_start, out);
}